// Round 14
// baseline (3164.394 us; speedup 1.0000x reference)
//
#include <hip/hip_runtime.h>
#include <hip/hip_bf16.h>
#include <cstdint>
#include <cstddef>

#define B_   8192
#define DX_  512
#define DZ_  1024
#define DY_  256
#define T_   4
#define NN_  6

typedef float f32x4 __attribute__((ext_vector_type(4)));
typedef short s16x8 __attribute__((ext_vector_type(8)));
typedef int   i32x4 __attribute__((ext_vector_type(4)));
typedef int   i32x8 __attribute__((ext_vector_type(8)));
typedef __hip_bfloat16 bf16;

__device__ __forceinline__ void gload_lds16(const void* g, void* l) {
  __builtin_amdgcn_global_load_lds(
      (const __attribute__((address_space(1))) void*)g,
      (__attribute__((address_space(3))) void*)l,
      16, 0, 0);
}

__device__ __forceinline__ float bf2f(unsigned short u) {
  union { unsigned int i; float f; } cv; cv.i = ((unsigned int)u) << 16; return cv.f;
}

// ---- one fused conversion kernel: fp32->bf16 copies + bias pack + PLAIN fp8 images
__device__ __forceinline__ void cv4(const float* __restrict__ s, bf16* __restrict__ d, long i) {
  float4 v = ((const float4*)s)[i];
  ushort4 o;
  bf16 a0 = __float2bfloat16(v.x); o.x = *(unsigned short*)&a0;
  bf16 a1 = __float2bfloat16(v.y); o.y = *(unsigned short*)&a1;
  bf16 a2 = __float2bfloat16(v.z); o.z = *(unsigned short*)&a2;
  bf16 a3 = __float2bfloat16(v.w); o.w = *(unsigned short*)&a3;
  ((ushort4*)d)[i] = o;
}
__device__ __forceinline__ void cv4f8(const float* __restrict__ src, unsigned char* __restrict__ dst,
                                      long row, int k0, int srcld, int srcoff) {
  float4 v = *(const float4*)(src + row * srcld + srcoff + k0);
  int p = __builtin_amdgcn_cvt_pk_fp8_f32(v.x, v.y, 0, 0);
  p = __builtin_amdgcn_cvt_pk_fp8_f32(v.z, v.w, p, 1);
  *(int*)(dst + row * DZ_ + k0) = p;   // plain row-major
}

__global__ void cvt_all_kernel(const float* __restrict__ Wn, const float* __restrict__ Wx,
                               const float* __restrict__ Wy, const float* __restrict__ Wu,
                               const float* __restrict__ Wq, const float* __restrict__ xs,
                               const float* __restrict__ ys0, const float* __restrict__ zs0,
                               const float* __restrict__ bu, const float* __restrict__ bq,
                               bf16* __restrict__ Wn_b, bf16* __restrict__ Wx_b,
                               bf16* __restrict__ Wy_b, bf16* __restrict__ Wuq_b,
                               bf16* __restrict__ xs_b, bf16* __restrict__ ysin_b,
                               float* __restrict__ buq,
                               unsigned char* __restrict__ Wnz8, unsigned char* __restrict__ z_a8) {
  const long NWN = (long)DZ_ * 3 * DZ_ / 4, NWX = (long)DZ_ * DX_ / 4,
             NWY = (long)DZ_ * DY_ / 4,     NWU = (long)DY_ * DZ_ / 4,
             NXS = (long)B_ * DX_ / 4,      NYS = (long)B_ * DY_ / 4,
             NBQ = 2 * DY_ / 4,
             NW8 = (long)DZ_ * DZ_ / 4,     NZ8 = (long)B_ * DZ_ / 4;
  const long total = NWN + NWX + NWY + 2 * NWU + NXS + NYS + NBQ + NW8 + NZ8;
  for (long i = (long)blockIdx.x * blockDim.x + threadIdx.x; i < total;
       i += (long)gridDim.x * blockDim.x) {
    long j = i;
    if (j < NWN) { cv4(Wn, Wn_b, j); continue; } j -= NWN;
    if (j < NWX) { cv4(Wx, Wx_b, j); continue; } j -= NWX;
    if (j < NWY) { cv4(Wy, Wy_b, j); continue; } j -= NWY;
    if (j < NWU) { cv4(Wu, Wuq_b, j); continue; } j -= NWU;
    if (j < NWU) { cv4(Wq, Wuq_b + (size_t)DY_ * DZ_, j); continue; } j -= NWU;
    if (j < NXS) { cv4(xs, xs_b, j); continue; } j -= NXS;
    if (j < NYS) { cv4(ys0, ysin_b, j); continue; } j -= NYS;
    if (j < NBQ) {
      float4 v = (j < DY_ / 4) ? ((const float4*)bu)[j] : ((const float4*)bq)[j - DY_ / 4];
      ((float4*)buq)[j] = v; continue;
    } j -= NBQ;
    if (j < NW8) {  // Wnz (cols 2048..3071 of Wn) -> fp8 plain
      long e = j * 4; long row = e >> 10; int k0 = (int)(e & 1023);
      cv4f8(Wn, Wnz8, row, k0, 3 * DZ_, 2 * DZ_); continue;
    } j -= NW8;
    {   // zs0 -> fp8 plain
      long e = j * 4; long row = e >> 10; int k0 = (int)(e & 1023);
      cv4f8(zs0, z_a8, row, k0, DZ_, 0);
    }
  }
}

// ================= bf16 GEMM (r10/r13-proven: BK=64, two-half lgkm schedule) =========
template<int ACT, int MODE, bool HASADD>   // ACT: 0 none, 1 tanh, 2 sigmoid
__global__ __launch_bounds__(512, 2)
void gemm_bt(const bf16* __restrict__ A, int lda,
             const bf16* __restrict__ W, int ldw,
             const float* __restrict__ bias,
             const bf16* __restrict__ add1,
             bf16* __restrict__ out_pre,
             void* __restrict__ out, void* __restrict__ out2,
             int N, int K)
{
  __shared__ __align__(16) char ldsc[3 * 49152];   // [buf][A 32KB | B 16KB]
  const int t    = threadIdx.x;
  const int lane = t & 63;
  const int wave = t >> 6;
  const int m0 = blockIdx.x * 256;
  const int n0 = blockIdx.y * 128;

  const int srow = t >> 3;
  const int q    = (t & 7) ^ ((t >> 3) & 7);
  const bf16* gA = A + (size_t)(m0 + srow) * lda + q * 8;
  const bf16* gB = W + (size_t)(n0 + srow) * ldw + q * 8;
  const int wb = wave * 1024;

  auto stage = [&](int kt) {
    char* base = ldsc + (kt % 3) * 49152;
    const int ko = kt << 6;
#pragma unroll
    for (int i = 0; i < 4; ++i)
      gload_lds16(gA + (size_t)(i * 64) * lda + ko, base + i * 8192 + wb);
#pragma unroll
    for (int i = 0; i < 2; ++i)
      gload_lds16(gB + (size_t)(i * 64) * ldw + ko, base + 32768 + i * 8192 + wb);
  };

  const int mo = (wave >> 1) * 64;
  const int no = (wave & 1) * 64;
  const int fr = lane & 15;
  const int g4 = lane >> 4;
  const int rb = g4 * 4;

  const int NT = K >> 6;

  float bv[4] = {0.f, 0.f, 0.f, 0.f};
  if (bias) {
#pragma unroll
    for (int j = 0; j < 4; ++j) bv[j] = bias[n0 + no + j * 16 + fr];
  }
  unsigned short adr[4][4][4];
  if (HASADD && MODE != 1) {
#pragma unroll
    for (int f = 0; f < 4; ++f)
#pragma unroll
      for (int j = 0; j < 4; ++j) {
        const unsigned short* p = (const unsigned short*)add1
            + (size_t)(m0 + mo + f * 16 + rb) * N + (n0 + no + j * 16 + fr);
#pragma unroll
        for (int r = 0; r < 4; ++r) adr[f][j][r] = p[(size_t)r * N];
      }
  }
  __builtin_amdgcn_sched_barrier(0);
  stage(0);
  stage(1);
  __builtin_amdgcn_sched_barrier(0);

  f32x4 acc[4][4];
#pragma unroll
  for (int f = 0; f < 4; ++f)
#pragma unroll
    for (int j = 0; j < 4; ++j)
#pragma unroll
      for (int r = 0; r < 4; ++r) {
        float v = bv[j];
        if (HASADD && MODE != 1) v += bf2f(adr[f][j][r]);
        acc[f][j][r] = v;
      }

  s16x8 a0[4], b0[4], a1[4], b1[4];
  auto ldfrags = [&](int kt, int s, s16x8* fa, s16x8* fb) {
    const char* pA = ldsc + (kt % 3) * 49152;
    const char* pB = pA + 32768;
    const int cb = ((s * 4 + g4) ^ (fr & 7)) * 16;
#pragma unroll
    for (int f = 0; f < 4; ++f) fa[f] = *(const s16x8*)(pA + (mo + f * 16 + fr) * 128 + cb);
#pragma unroll
    for (int j = 0; j < 4; ++j) fb[j] = *(const s16x8*)(pB + (no + j * 16 + fr) * 128 + cb);
  };
  auto domfma = [&](const s16x8* fa, const s16x8* fb) {
    __builtin_amdgcn_s_setprio(1);
#pragma unroll
    for (int f = 0; f < 4; ++f)
#pragma unroll
      for (int j = 0; j < 4; ++j)
        acc[f][j] = __builtin_amdgcn_mfma_f32_16x16x32_bf16(fa[f], fb[j], acc[f][j], 0, 0, 0);
    __builtin_amdgcn_s_setprio(0);
  };

  asm volatile("s_waitcnt vmcnt(6)" ::: "memory");
  __builtin_amdgcn_s_barrier();
  __builtin_amdgcn_sched_barrier(0);

  for (int kt = 0; kt < NT; ++kt) {
    ldfrags(kt, 0, a0, b0);
    ldfrags(kt, 1, a1, b1);
    if (kt + 2 < NT) stage(kt + 2);
    __builtin_amdgcn_sched_barrier(0);
    asm volatile("s_waitcnt lgkmcnt(8)" ::: "memory");
    __builtin_amdgcn_sched_barrier(0);
    domfma(a0, b0);
    asm volatile("s_waitcnt lgkmcnt(0)" ::: "memory");
    __builtin_amdgcn_sched_barrier(0);
    domfma(a1, b1);
    if (kt + 2 < NT)      asm volatile("s_waitcnt vmcnt(6)" ::: "memory");
    else if (kt + 1 < NT) asm volatile("s_waitcnt vmcnt(0)" ::: "memory");
    if (kt + 1 < NT) {
      __builtin_amdgcn_s_barrier();
      __builtin_amdgcn_sched_barrier(0);
    }
  }

#pragma unroll
  for (int f = 0; f < 4; ++f) {
#pragma unroll
    for (int j = 0; j < 4; ++j) {
      const int n = n0 + no + j * 16 + fr;
#pragma unroll
      for (int r = 0; r < 4; ++r) {
        const int m = m0 + mo + f * 16 + rb + r;
        float v = acc[f][j][r];
        if (MODE == 1) {
          out_pre[(size_t)m * N + n] = __float2bfloat16(v);
          v += bf2f(((const unsigned short*)add1)[(size_t)m * N + n]);
        }
        if (ACT == 1)      { float e = __expf(2.f * v); v = 1.f - 2.f / (e + 1.f); }
        else if (ACT == 2) v = 1.f / (1.f + __expf(-v));
        if (MODE == 2) {
          if (n < DY_) ((float*)out)[(size_t)m * DY_ + n] = v;
          else         ((float*)out2)[(size_t)m * DY_ + (n - DY_)] = v;
        } else {
          ((bf16*)out)[(size_t)m * N + n] = __float2bfloat16(v);
        }
      }
    }
  }
}

// ================= MX fp8 GEMM — r12 layout-verified, register-pressure-fixed ========
// out = tanh(add1 + A8 @ W8.T); A8/W8 fp8 e4m3, PLAIN row-major [*, DZ_].
// mfma_scale_f32_16x16x128_f8f6f4, all E8M0 scales = 127 (2^0): values identical to
// plain fp8 (r12 measured absmax == r11), 2x the MFMA rate. K-tile 128 (48KB tiles),
// 3-buffer rotation (144KB, 1 block/CU), depth-2 prefetch, counted vmcnt(6).
// Register fix vs r12: bv[4] tuples resident (32 VGPR); A-tuples STREAMED one per f
// inside the MFMA phase (shufflevector of two b128 reads -> clean 8-reg SSA).
// Peak liveness ~ acc64 + bv32 + a8-24 + addr => no spill (r12 held 64 operand regs
// + 64 acc live -> scratch, 9x slowdown).
// LDS swizzle: physical 16B-unit = logical ^ (row&7) via source-permuted global
// staging q8=(t&7)^(row&7) (linear gload dest); read at p0=((2g4)^(fr&7))*16, p1=p0^16.
__device__ __forceinline__ i32x8 ld8(const char* rp, int p0, int p1) {
  i32x4 lo = *(const i32x4*)(rp + p0);
  i32x4 hi = *(const i32x4*)(rp + p1);
  return __builtin_shufflevector(lo, hi, 0, 1, 2, 3, 4, 5, 6, 7);
}

__global__ __launch_bounds__(512, 2)
void gemm_f8(const unsigned char* __restrict__ A8,
             const unsigned char* __restrict__ W8,
             const bf16* __restrict__ add1,
             unsigned char* __restrict__ out8,
             bf16* __restrict__ out16)
{
  __shared__ __align__(16) char ldsc[3 * 49152];   // [buf][A 32KB | B 16KB]
  const int t    = threadIdx.x;
  const int lane = t & 63;
  const int wave = t >> 6;
  const int m0 = blockIdx.x * 256;
  const int n0 = blockIdx.y * 128;

  // staging: row = srow + i*64, source-permuted 16B unit q8 = (t&7) ^ (row&7)
  const int srow = t >> 3;                      // 0..63 (+64*i per gload)
  const int q8   = (t & 7) ^ ((t >> 3) & 7);
  const unsigned char* gA = A8 + (size_t)(m0 + srow) * DZ_ + q8 * 16;
  const unsigned char* gB = W8 + (size_t)(n0 + srow) * DZ_ + q8 * 16;
  const int wb = wave * 1024;

  auto stage = [&](int kt) {                    // 6 gloads: A 4x8KB, B 2x8KB
    char* base = ldsc + (kt % 3) * 49152;
    const int ko = kt << 7;                     // K-tile = 128 fp8 bytes
#pragma unroll
    for (int i = 0; i < 4; ++i)
      gload_lds16(gA + (size_t)(i * 64) * DZ_ + ko, base + i * 8192 + wb);
#pragma unroll
    for (int i = 0; i < 2; ++i)
      gload_lds16(gB + (size_t)(i * 64) * DZ_ + ko, base + 32768 + i * 8192 + wb);
  };

  const int mo = (wave >> 1) * 64;
  const int no = (wave & 1) * 64;
  const int fr = lane & 15;
  const int g4 = lane >> 4;
  const int rb = g4 * 4;
  const int p0 = (((g4 << 1) ^ (fr & 7)) << 4);   // swizzled byte offset, k-bytes 0..15
  const int p1 = p0 ^ 16;                          // k-bytes 16..31

  const int NT = DZ_ >> 7;                      // 8

  unsigned short adr[4][4][4];
#pragma unroll
  for (int f = 0; f < 4; ++f)
#pragma unroll
    for (int j = 0; j < 4; ++j) {
      const unsigned short* p = (const unsigned short*)add1
          + (size_t)(m0 + mo + f * 16 + rb) * DZ_ + (n0 + no + j * 16 + fr);
#pragma unroll
      for (int r = 0; r < 4; ++r) adr[f][j][r] = p[(size_t)r * DZ_];
    }
  __builtin_amdgcn_sched_barrier(0);
  stage(0); stage(1);
  __builtin_amdgcn_sched_barrier(0);

  f32x4 acc[4][4];
#pragma unroll
  for (int f = 0; f < 4; ++f)
#pragma unroll
    for (int j = 0; j < 4; ++j)
#pragma unroll
      for (int r = 0; r < 4; ++r) acc[f][j][r] = bf2f(adr[f][j][r]);

  asm volatile("s_waitcnt vmcnt(6)" ::: "memory");   // tile 0 resident
  __builtin_amdgcn_s_barrier();
  __builtin_amdgcn_sched_barrier(0);

  for (int kt = 0; kt < NT; ++kt) {
    const char* pA = ldsc + (kt % 3) * 49152;
    const char* pB = pA + 32768;
    // B tuples resident for the whole tile (32 VGPRs)
    i32x8 bv[4];
#pragma unroll
    for (int j = 0; j < 4; ++j)
      bv[j] = ld8(pB + (no + j * 16 + fr) * 128, p0, p1);
    if (kt + 2 < NT) stage(kt + 2);
    // A tuples streamed: one live at a time (compiler inserts lgkm waits on use)
    __builtin_amdgcn_s_setprio(1);
#pragma unroll
    for (int f = 0; f < 4; ++f) {
      i32x8 a = ld8(pA + (mo + f * 16 + fr) * 128, p0, p1);
#pragma unroll
      for (int j = 0; j < 4; ++j)
        acc[f][j] = __builtin_amdgcn_mfma_scale_f32_16x16x128_f8f6f4(
            a, bv[j], acc[f][j], 0, 0, 0, 0x7f7f7f7f, 0, 0x7f7f7f7f);
    }
    __builtin_amdgcn_s_setprio(0);
    asm volatile("s_waitcnt lgkmcnt(0)" ::: "memory");   // reads drained before barrier
    __builtin_amdgcn_sched_barrier(0);
    if (kt + 2 < NT)      asm volatile("s_waitcnt vmcnt(6)" ::: "memory");
    else if (kt + 1 < NT) asm volatile("s_waitcnt vmcnt(0)" ::: "memory");
    if (kt + 1 < NT) {
      __builtin_amdgcn_s_barrier();
      __builtin_amdgcn_sched_barrier(0);
    }
  }

  // epilogue: tanh; plain fp8 and/or bf16 outputs
#pragma unroll
  for (int f = 0; f < 4; ++f) {
#pragma unroll
    for (int j = 0; j < 4; ++j) {
      const int n = n0 + no + j * 16 + fr;
#pragma unroll
      for (int r = 0; r < 4; ++r) {
        const int m = m0 + mo + f * 16 + rb + r;
        float v = acc[f][j][r];
        float e = __expf(2.f * v); v = 1.f - 2.f / (e + 1.f);
        if (out8)  out8[(size_t)m * DZ_ + n] =
            (unsigned char)__builtin_amdgcn_cvt_pk_fp8_f32(v, v, 0, 0);
        if (out16) out16[(size_t)m * DZ_ + n] = __float2bfloat16(v);
      }
    }
  }
}

extern "C" void kernel_launch(void* const* d_in, const int* in_sizes, int n_in,
                              void* d_out, int out_size, void* d_ws, size_t ws_size,
                              hipStream_t stream) {
  const float* xs  = (const float*)d_in[0];
  const float* Wx  = (const float*)d_in[1];
  const float* bx  = (const float*)d_in[2];
  const float* Wy  = (const float*)d_in[3];
  const float* by  = (const float*)d_in[4];
  const float* Wn  = (const float*)d_in[5];
  const float* bn  = (const float*)d_in[6];
  const float* Wu  = (const float*)d_in[7];
  const float* bu  = (const float*)d_in[8];
  const float* Wq  = (const float*)d_in[9];
  const float* bq  = (const float*)d_in[10];
  const float* ys0 = (const float*)d_in[11];
  const float* zs0 = (const float*)d_in[12];

  char* ws = (char*)d_ws;
  size_t off = 0;
  auto take = [&](size_t bytes) -> char* {
    char* p = ws + off;
    off += (bytes + 255) & ~(size_t)255;
    return p;
  };

  bf16*  Wn_b   = (bf16*)take((size_t)DZ_ * 3 * DZ_ * 2);
  bf16*  Wx_b   = (bf16*)take((size_t)DZ_ * DX_ * 2);
  bf16*  Wy_b   = (bf16*)take((size_t)DZ_ * DY_ * 2);
  bf16*  Wuq_b  = (bf16*)take((size_t)2 * DY_ * DZ_ * 2);
  float* buq    = (float*)take((size_t)2 * DY_ * 4);
  bf16*  ys_b   = (bf16*)take((size_t)B_ * DZ_ * 2);
  bf16*  z_a    = (bf16*)take((size_t)B_ * DZ_ * 2);
  bf16*  z_b    = (bf16*)take((size_t)B_ * DZ_ * 2);
  bf16*  cx     = (bf16*)take((size_t)B_ * DZ_ * 2);
  bf16*  cy     = (bf16*)take((size_t)B_ * DZ_ * 2);
  bf16*  c      = (bf16*)take((size_t)B_ * DZ_ * 2);
  unsigned char* Wnz8 = (unsigned char*)take((size_t)DZ_ * DZ_);
  unsigned char* z_a8 = (unsigned char*)take((size_t)B_ * DZ_);
  unsigned char* z_b8 = (unsigned char*)take((size_t)B_ * DZ_);
  // aliases into regions not yet live at time of use:
  bf16* xs_b   = c;                                         // dead before c first written
  bf16* ysin_b = (bf16*)((char*)c + (size_t)B_ * DX_ * 2);  // 8.4+4.2 MB <= 16.7 MB
  bf16* xse_b  = cy;                                        // dead before cy first written

  cvt_all_kernel<<<2048, 256, 0, stream>>>(Wn, Wx, Wy, Wu, Wq, xs, ys0, zs0, bu, bq,
                                           Wn_b, Wx_b, Wy_b, Wuq_b,
                                           xs_b, ysin_b, buq, Wnz8, z_a8);

  const dim3 blk(512);
  const dim3 gz(B_ / 256, DZ_ / 128);   // 32 x 8 = 256 blocks = 1/CU
  const dim3 gh(B_ / 256, 4);           // head: N=512 -> 32 x 4

  // xs_e = xs@Wx.T + bx  (bf16)
  gemm_bt<0, 0, false><<<gz, blk, 0, stream>>>(xs_b, DX_, Wx_b, DX_, bx, nullptr, nullptr, xse_b, nullptr, DZ_, DX_);
  // ys_e = ys0@Wy.T + by (bf16)
  gemm_bt<0, 0, false><<<gz, blk, 0, stream>>>(ysin_b, DY_, Wy_b, DY_, by, nullptr, nullptr, ys_b, nullptr, DZ_, DY_);
  // cx = xs_e@Wnx.T (bf16)
  gemm_bt<0, 0, false><<<gz, blk, 0, stream>>>(xse_b, DZ_, Wn_b, 3 * DZ_, nullptr, nullptr, nullptr, cx, nullptr, DZ_, DZ_);

  unsigned char* zc8 = z_a8;
  unsigned char* zn8 = z_b8;
  for (int tt = 0; tt < T_; ++tt) {
    // cy = ys_e@Wny.T + bn ; c = cy + cx  (bf16, one GEMM)
    gemm_bt<0, 1, true><<<gz, blk, 0, stream>>>(ys_b, DZ_, Wn_b + DZ_, 3 * DZ_, bn, cx, cy, c, nullptr, DZ_, DZ_);
    if (tt < T_ - 1) {
      // no-grad phase: MX-fp8 z-steps; bf16 shadow only at tt==2's last step (tt=3 input)
      for (int i = 0; i < NN_; ++i) {
        bf16* shadow = (tt == T_ - 2 && i == NN_ - 1) ? z_a : nullptr;
        gemm_f8<<<gz, blk, 0, stream>>>(zc8, Wnz8, c, zn8, shadow);
        unsigned char* t8 = zc8; zc8 = zn8; zn8 = t8;
      }
      // ys_e = tanh(cy + z@Wnz.T)  — MX-fp8 (noise contracts through >=7 later steps)
      gemm_f8<<<gz, blk, 0, stream>>>(zc8, Wnz8, cy, nullptr, ys_b);
    } else {
      // grad-enabled block: bf16 z-steps from the tt=2 shadow
      bf16* zc = z_a;
      bf16* zn = z_b;
      for (int i = 0; i < NN_; ++i) {
        gemm_bt<1, 0, true><<<gz, blk, 0, stream>>>(zc, DZ_, Wn_b + 2 * DZ_, 3 * DZ_, nullptr, c, nullptr, zn, nullptr, DZ_, DZ_);
        bf16* tmp = zc; zc = zn; zn = tmp;
      }
      // ys_e = tanh(cy + z@Wnz.T)  (bf16)
      gemm_bt<1, 0, true><<<gz, blk, 0, stream>>>(zc, DZ_, Wn_b + 2 * DZ_, 3 * DZ_, nullptr, cy, nullptr, ys_b, nullptr, DZ_, DZ_);
    }
  }

  float* outp = (float*)d_out;
  // y_hat | q_hat = sigmoid(ys_e@[Wu;Wq].T + [bu;bq]) — one N=512 GEMM, split store
  gemm_bt<2, 2, false><<<gh, blk, 0, stream>>>(ys_b, DZ_, Wuq_b, DZ_, buq, nullptr, nullptr,
                                               outp, outp + (size_t)B_ * DY_, 2 * DY_, DZ_);
}

// Round 15
// 838.111 us; speedup vs baseline: 3.7756x; 3.7756x over previous
//
#include <hip/hip_runtime.h>
#include <hip/hip_bf16.h>
#include <cstdint>
#include <cstddef>

#define B_   8192
#define DX_  512
#define DZ_  1024
#define DY_  256
#define T_   4
#define NN_  6

typedef float f32x4 __attribute__((ext_vector_type(4)));
typedef short s16x8 __attribute__((ext_vector_type(8)));
typedef long i64x2 __attribute__((ext_vector_type(2)));
typedef __hip_bfloat16 bf16;

__device__ __forceinline__ void gload_lds16(const void* g, void* l) {
  __builtin_amdgcn_global_load_lds(
      (const __attribute__((address_space(1))) void*)g,
      (__attribute__((address_space(3))) void*)l,
      16, 0, 0);
}

__device__ __forceinline__ float bf2f(unsigned short u) {
  union { unsigned int i; float f; } cv; cv.i = ((unsigned int)u) << 16; return cv.f;
}

// fp8 k-permute: within each 64-col group, byte for col n goes to
// perm(n) = g4*16 + slice*8 + j  (g4=(n>>3)&3, slice=(n>>5)&1, j=n&7), so a b128
// LDS read at chunk g4 yields both K=32 slices for mfma_16x16x32_fp8_fp8.
__device__ __forceinline__ int permb(int n) {
  return (n & ~63) | (((n >> 3) & 3) << 4) | (((n >> 5) & 1) << 3) | (n & 7);
}

// ---- one fused conversion kernel: fp32->bf16 copies + bias pack + fp8 images
__device__ __forceinline__ void cv4(const float* __restrict__ s, bf16* __restrict__ d, long i) {
  float4 v = ((const float4*)s)[i];
  ushort4 o;
  bf16 a0 = __float2bfloat16(v.x); o.x = *(unsigned short*)&a0;
  bf16 a1 = __float2bfloat16(v.y); o.y = *(unsigned short*)&a1;
  bf16 a2 = __float2bfloat16(v.z); o.z = *(unsigned short*)&a2;
  bf16 a3 = __float2bfloat16(v.w); o.w = *(unsigned short*)&a3;
  ((ushort4*)d)[i] = o;
}
__device__ __forceinline__ void cv4f8(const float* __restrict__ src, unsigned char* __restrict__ dst,
                                      long row, int k0, int srcld, int srcoff) {
  float4 v = *(const float4*)(src + row * srcld + srcoff + k0);
  int p = __builtin_amdgcn_cvt_pk_fp8_f32(v.x, v.y, 0, 0);
  p = __builtin_amdgcn_cvt_pk_fp8_f32(v.z, v.w, p, 1);
  *(int*)(dst + row * DZ_ + permb(k0)) = p;   // k0 % 4 == 0 -> 4 contiguous bytes
}

__global__ void cvt_all_kernel(const float* __restrict__ Wn, const float* __restrict__ Wx,
                               const float* __restrict__ Wy, const float* __restrict__ Wu,
                               const float* __restrict__ Wq, const float* __restrict__ xs,
                               const float* __restrict__ ys0, const float* __restrict__ zs0,
                               const float* __restrict__ bu, const float* __restrict__ bq,
                               bf16* __restrict__ Wn_b, bf16* __restrict__ Wx_b,
                               bf16* __restrict__ Wy_b, bf16* __restrict__ Wuq_b,
                               bf16* __restrict__ xs_b, bf16* __restrict__ ysin_b,
                               float* __restrict__ buq,
                               unsigned char* __restrict__ Wnz8, unsigned char* __restrict__ z_a8) {
  const long NWN = (long)DZ_ * 3 * DZ_ / 4, NWX = (long)DZ_ * DX_ / 4,
             NWY = (long)DZ_ * DY_ / 4,     NWU = (long)DY_ * DZ_ / 4,
             NXS = (long)B_ * DX_ / 4,      NYS = (long)B_ * DY_ / 4,
             NBQ = 2 * DY_ / 4,
             NW8 = (long)DZ_ * DZ_ / 4,     NZ8 = (long)B_ * DZ_ / 4;
  const long total = NWN + NWX + NWY + 2 * NWU + NXS + NYS + NBQ + NW8 + NZ8;
  for (long i = (long)blockIdx.x * blockDim.x + threadIdx.x; i < total;
       i += (long)gridDim.x * blockDim.x) {
    long j = i;
    if (j < NWN) { cv4(Wn, Wn_b, j); continue; } j -= NWN;
    if (j < NWX) { cv4(Wx, Wx_b, j); continue; } j -= NWX;
    if (j < NWY) { cv4(Wy, Wy_b, j); continue; } j -= NWY;
    if (j < NWU) { cv4(Wu, Wuq_b, j); continue; } j -= NWU;
    if (j < NWU) { cv4(Wq, Wuq_b + (size_t)DY_ * DZ_, j); continue; } j -= NWU;
    if (j < NXS) { cv4(xs, xs_b, j); continue; } j -= NXS;
    if (j < NYS) { cv4(ys0, ysin_b, j); continue; } j -= NYS;
    if (j < NBQ) {
      float4 v = (j < DY_ / 4) ? ((const float4*)bu)[j] : ((const float4*)bq)[j - DY_ / 4];
      ((float4*)buq)[j] = v; continue;
    } j -= NBQ;
    if (j < NW8) {  // Wnz (cols 2048..3071 of Wn) -> fp8 k-permuted
      long e = j * 4; long row = e >> 10; int k0 = (int)(e & 1023);
      cv4f8(Wn, Wnz8, row, k0, 3 * DZ_, 2 * DZ_); continue;
    } j -= NW8;
    {   // zs0 -> fp8 k-permuted
      long e = j * 4; long row = e >> 10; int k0 = (int)(e & 1023);
      cv4f8(zs0, z_a8, row, k0, DZ_, 0);
    }
  }
}

// ================= bf16 GEMM (r10/r13-proven: BK=64, two-half lgkm schedule) =========
template<int ACT, int MODE, bool HASADD>   // ACT: 0 none, 1 tanh, 2 sigmoid
__global__ __launch_bounds__(512, 2)
void gemm_bt(const bf16* __restrict__ A, int lda,
             const bf16* __restrict__ W, int ldw,
             const float* __restrict__ bias,
             const bf16* __restrict__ add1,
             bf16* __restrict__ out_pre,
             void* __restrict__ out, void* __restrict__ out2,
             int N, int K)
{
  __shared__ __align__(16) char ldsc[3 * 49152];   // [buf][A 32KB | B 16KB]
  const int t    = threadIdx.x;
  const int lane = t & 63;
  const int wave = t >> 6;
  const int m0 = blockIdx.x * 256;
  const int n0 = blockIdx.y * 128;

  const int srow = t >> 3;
  const int q    = (t & 7) ^ ((t >> 3) & 7);
  const bf16* gA = A + (size_t)(m0 + srow) * lda + q * 8;
  const bf16* gB = W + (size_t)(n0 + srow) * ldw + q * 8;
  const int wb = wave * 1024;

  auto stage = [&](int kt) {
    char* base = ldsc + (kt % 3) * 49152;
    const int ko = kt << 6;
#pragma unroll
    for (int i = 0; i < 4; ++i)
      gload_lds16(gA + (size_t)(i * 64) * lda + ko, base + i * 8192 + wb);
#pragma unroll
    for (int i = 0; i < 2; ++i)
      gload_lds16(gB + (size_t)(i * 64) * ldw + ko, base + 32768 + i * 8192 + wb);
  };

  const int mo = (wave >> 1) * 64;
  const int no = (wave & 1) * 64;
  const int fr = lane & 15;
  const int g4 = lane >> 4;
  const int rb = g4 * 4;

  const int NT = K >> 6;

  float bv[4] = {0.f, 0.f, 0.f, 0.f};
  if (bias) {
#pragma unroll
    for (int j = 0; j < 4; ++j) bv[j] = bias[n0 + no + j * 16 + fr];
  }
  unsigned short adr[4][4][4];
  if (HASADD && MODE != 1) {
#pragma unroll
    for (int f = 0; f < 4; ++f)
#pragma unroll
      for (int j = 0; j < 4; ++j) {
        const unsigned short* p = (const unsigned short*)add1
            + (size_t)(m0 + mo + f * 16 + rb) * N + (n0 + no + j * 16 + fr);
#pragma unroll
        for (int r = 0; r < 4; ++r) adr[f][j][r] = p[(size_t)r * N];
      }
  }
  __builtin_amdgcn_sched_barrier(0);
  stage(0);
  stage(1);
  __builtin_amdgcn_sched_barrier(0);

  f32x4 acc[4][4];
#pragma unroll
  for (int f = 0; f < 4; ++f)
#pragma unroll
    for (int j = 0; j < 4; ++j)
#pragma unroll
      for (int r = 0; r < 4; ++r) {
        float v = bv[j];
        if (HASADD && MODE != 1) v += bf2f(adr[f][j][r]);
        acc[f][j][r] = v;
      }

  s16x8 a0[4], b0[4], a1[4], b1[4];
  auto ldfrags = [&](int kt, int s, s16x8* fa, s16x8* fb) {
    const char* pA = ldsc + (kt % 3) * 49152;
    const char* pB = pA + 32768;
    const int cb = ((s * 4 + g4) ^ (fr & 7)) * 16;
#pragma unroll
    for (int f = 0; f < 4; ++f) fa[f] = *(const s16x8*)(pA + (mo + f * 16 + fr) * 128 + cb);
#pragma unroll
    for (int j = 0; j < 4; ++j) fb[j] = *(const s16x8*)(pB + (no + j * 16 + fr) * 128 + cb);
  };
  auto domfma = [&](const s16x8* fa, const s16x8* fb) {
    __builtin_amdgcn_s_setprio(1);
#pragma unroll
    for (int f = 0; f < 4; ++f)
#pragma unroll
      for (int j = 0; j < 4; ++j)
        acc[f][j] = __builtin_amdgcn_mfma_f32_16x16x32_bf16(fa[f], fb[j], acc[f][j], 0, 0, 0);
    __builtin_amdgcn_s_setprio(0);
  };

  asm volatile("s_waitcnt vmcnt(6)" ::: "memory");
  __builtin_amdgcn_s_barrier();
  __builtin_amdgcn_sched_barrier(0);

  for (int kt = 0; kt < NT; ++kt) {
    ldfrags(kt, 0, a0, b0);
    ldfrags(kt, 1, a1, b1);
    if (kt + 2 < NT) stage(kt + 2);
    __builtin_amdgcn_sched_barrier(0);
    asm volatile("s_waitcnt lgkmcnt(8)" ::: "memory");
    __builtin_amdgcn_sched_barrier(0);
    domfma(a0, b0);
    asm volatile("s_waitcnt lgkmcnt(0)" ::: "memory");
    __builtin_amdgcn_sched_barrier(0);
    domfma(a1, b1);
    if (kt + 2 < NT)      asm volatile("s_waitcnt vmcnt(6)" ::: "memory");
    else if (kt + 1 < NT) asm volatile("s_waitcnt vmcnt(0)" ::: "memory");
    if (kt + 1 < NT) {
      __builtin_amdgcn_s_barrier();
      __builtin_amdgcn_sched_barrier(0);
    }
  }

#pragma unroll
  for (int f = 0; f < 4; ++f) {
#pragma unroll
    for (int j = 0; j < 4; ++j) {
      const int n = n0 + no + j * 16 + fr;
#pragma unroll
      for (int r = 0; r < 4; ++r) {
        const int m = m0 + mo + f * 16 + rb + r;
        float v = acc[f][j][r];
        if (MODE == 1) {
          out_pre[(size_t)m * N + n] = __float2bfloat16(v);
          v += bf2f(((const unsigned short*)add1)[(size_t)m * N + n]);
        }
        if (ACT == 1)      { float e = __expf(2.f * v); v = 1.f - 2.f / (e + 1.f); }
        else if (ACT == 2) v = 1.f / (1.f + __expf(-v));
        if (MODE == 2) {
          if (n < DY_) ((float*)out)[(size_t)m * DY_ + n] = v;
          else         ((float*)out2)[(size_t)m * DY_ + (n - DY_)] = v;
        } else {
          ((bf16*)out)[(size_t)m * N + n] = __float2bfloat16(v);
        }
      }
    }
  }
}

// ================= fp8 GEMM (r10-proven kernel; r15: 3-buffer LDS = 72KB) =========
// out = tanh(add1 + A8 @ W8.T); A8/W8 fp8 e4m3, k-permuted global layout.
// out8 (fp8, permuted) optional; out16 (bf16) optional.
// r15 change (single variable): 4x24KB -> 3x24KB LDS (96->72KB) => 2 blocks/CU
// (needs VGPR<=128: __launch_bounds__(512,4)). Two independent barrier domains per
// CU fill each other's stalls (m114). Depth-2 prefetch: stage(kt+2) overwrites tile
// kt-1's buffer, whose reads were drained by lgkmcnt(0) before the previous barrier.
// In-flight after stage = 6 loads -> vmcnt(3) guarantees tile kt+1 resident.
__global__ __launch_bounds__(512, 4)
void gemm_f8(const unsigned char* __restrict__ A8,
             const unsigned char* __restrict__ W8,
             const bf16* __restrict__ add1,
             unsigned char* __restrict__ out8,
             bf16* __restrict__ out16)
{
  __shared__ __align__(16) char ldsc[3 * 24576];   // [buf][A 16KB | B 8KB]
  const int t    = threadIdx.x;
  const int lane = t & 63;
  const int wave = t >> 6;
  const int m0 = blockIdx.x * 256;
  const int n0 = blockIdx.y * 128;

  const int srow = t >> 2;
  const int q    = (t & 3) ^ ((t >> 3) & 3);
  const unsigned char* gA = A8 + (size_t)(m0 + srow) * DZ_ + q * 16;
  const unsigned char* gB = W8 + (size_t)(n0 + srow) * DZ_ + q * 16;
  const int wb = wave * 1024;

  auto stage = [&](int kt) {                 // 3 gloads: A 2x8KB, B 1x8KB
    char* base = ldsc + (kt % 3) * 24576;
    const int ko = kt << 6;
    gload_lds16(gA + ko, base + wb);
    gload_lds16(gA + (size_t)128 * DZ_ + ko, base + 8192 + wb);
    gload_lds16(gB + ko, base + 16384 + wb);
  };

  const int mo = (wave >> 1) * 64;
  const int no = (wave & 1) * 64;
  const int fr = lane & 15;
  const int g4 = lane >> 4;
  const int rb = g4 * 4;
  const int cb = (g4 ^ ((fr >> 1) & 3)) * 16;   // swizzled 16B chunk

  const int NT = DZ_ >> 6;                      // 16

  unsigned short adr[4][4][4];
#pragma unroll
  for (int f = 0; f < 4; ++f)
#pragma unroll
    for (int j = 0; j < 4; ++j) {
      const unsigned short* p = (const unsigned short*)add1
          + (size_t)(m0 + mo + f * 16 + rb) * DZ_ + (n0 + no + j * 16 + fr);
#pragma unroll
      for (int r = 0; r < 4; ++r) adr[f][j][r] = p[(size_t)r * DZ_];
    }
  __builtin_amdgcn_sched_barrier(0);
  stage(0); stage(1);
  __builtin_amdgcn_sched_barrier(0);

  f32x4 acc[4][4];
#pragma unroll
  for (int f = 0; f < 4; ++f)
#pragma unroll
    for (int j = 0; j < 4; ++j)
#pragma unroll
      for (int r = 0; r < 4; ++r) acc[f][j][r] = bf2f(adr[f][j][r]);

  asm volatile("s_waitcnt vmcnt(3)" ::: "memory");   // tile 0 resident
  __builtin_amdgcn_s_barrier();
  __builtin_amdgcn_sched_barrier(0);

  for (int kt = 0; kt < NT; ++kt) {
    const char* pA = ldsc + (kt % 3) * 24576;
    const char* pB = pA + 16384;
    i64x2 av[4], bv[4];
#pragma unroll
    for (int f = 0; f < 4; ++f) av[f] = *(const i64x2*)(pA + (mo + f * 16 + fr) * 64 + cb);
#pragma unroll
    for (int j = 0; j < 4; ++j) bv[j] = *(const i64x2*)(pB + (no + j * 16 + fr) * 64 + cb);
    if (kt + 2 < NT) stage(kt + 2);
    __builtin_amdgcn_sched_barrier(0);
    asm volatile("s_waitcnt lgkmcnt(0)" ::: "memory");
    __builtin_amdgcn_sched_barrier(0);
    __builtin_amdgcn_s_setprio(1);
#pragma unroll
    for (int f = 0; f < 4; ++f)
#pragma unroll
      for (int j = 0; j < 4; ++j) {
        acc[f][j] = __builtin_amdgcn_mfma_f32_16x16x32_fp8_fp8(av[f][0], bv[j][0], acc[f][j], 0, 0, 0);
        acc[f][j] = __builtin_amdgcn_mfma_f32_16x16x32_fp8_fp8(av[f][1], bv[j][1], acc[f][j], 0, 0, 0);
      }
    __builtin_amdgcn_s_setprio(0);
    const int rem = NT - 1 - kt;
    if (rem >= 2)      asm volatile("s_waitcnt vmcnt(3)" ::: "memory");
    else if (rem == 1) asm volatile("s_waitcnt vmcnt(0)" ::: "memory");
    if (rem >= 1) {
      __builtin_amdgcn_s_barrier();
      __builtin_amdgcn_sched_barrier(0);
    }
  }

  // epilogue: tanh; fp8 (permuted) and/or bf16 outputs
#pragma unroll
  for (int f = 0; f < 4; ++f) {
#pragma unroll
    for (int j = 0; j < 4; ++j) {
      const int n = n0 + no + j * 16 + fr;
      const int np = permb(n);
#pragma unroll
      for (int r = 0; r < 4; ++r) {
        const int m = m0 + mo + f * 16 + rb + r;
        float v = acc[f][j][r];
        float e = __expf(2.f * v); v = 1.f - 2.f / (e + 1.f);
        if (out8)  out8[(size_t)m * DZ_ + np] =
            (unsigned char)__builtin_amdgcn_cvt_pk_fp8_f32(v, v, 0, 0);
        if (out16) out16[(size_t)m * DZ_ + n] = __float2bfloat16(v);
      }
    }
  }
}

extern "C" void kernel_launch(void* const* d_in, const int* in_sizes, int n_in,
                              void* d_out, int out_size, void* d_ws, size_t ws_size,
                              hipStream_t stream) {
  const float* xs  = (const float*)d_in[0];
  const float* Wx  = (const float*)d_in[1];
  const float* bx  = (const float*)d_in[2];
  const float* Wy  = (const float*)d_in[3];
  const float* by  = (const float*)d_in[4];
  const float* Wn  = (const float*)d_in[5];
  const float* bn  = (const float*)d_in[6];
  const float* Wu  = (const float*)d_in[7];
  const float* bu  = (const float*)d_in[8];
  const float* Wq  = (const float*)d_in[9];
  const float* bq  = (const float*)d_in[10];
  const float* ys0 = (const float*)d_in[11];
  const float* zs0 = (const float*)d_in[12];

  char* ws = (char*)d_ws;
  size_t off = 0;
  auto take = [&](size_t bytes) -> char* {
    char* p = ws + off;
    off += (bytes + 255) & ~(size_t)255;
    return p;
  };

  bf16*  Wn_b   = (bf16*)take((size_t)DZ_ * 3 * DZ_ * 2);
  bf16*  Wx_b   = (bf16*)take((size_t)DZ_ * DX_ * 2);
  bf16*  Wy_b   = (bf16*)take((size_t)DZ_ * DY_ * 2);
  bf16*  Wuq_b  = (bf16*)take((size_t)2 * DY_ * DZ_ * 2);
  float* buq    = (float*)take((size_t)2 * DY_ * 4);
  bf16*  ys_b   = (bf16*)take((size_t)B_ * DZ_ * 2);
  bf16*  z_a    = (bf16*)take((size_t)B_ * DZ_ * 2);
  bf16*  z_b    = (bf16*)take((size_t)B_ * DZ_ * 2);
  bf16*  cx     = (bf16*)take((size_t)B_ * DZ_ * 2);
  bf16*  cy     = (bf16*)take((size_t)B_ * DZ_ * 2);
  bf16*  c      = (bf16*)take((size_t)B_ * DZ_ * 2);
  unsigned char* Wnz8 = (unsigned char*)take((size_t)DZ_ * DZ_);
  unsigned char* z_a8 = (unsigned char*)take((size_t)B_ * DZ_);
  unsigned char* z_b8 = (unsigned char*)take((size_t)B_ * DZ_);
  // aliases into regions not yet live at time of use:
  bf16* xs_b   = c;                                         // dead before c first written
  bf16* ysin_b = (bf16*)((char*)c + (size_t)B_ * DX_ * 2);  // 8.4+4.2 MB <= 16.7 MB
  bf16* xse_b  = cy;                                        // dead before cy first written

  cvt_all_kernel<<<2048, 256, 0, stream>>>(Wn, Wx, Wy, Wu, Wq, xs, ys0, zs0, bu, bq,
                                           Wn_b, Wx_b, Wy_b, Wuq_b,
                                           xs_b, ysin_b, buq, Wnz8, z_a8);

  const dim3 blk(512);
  const dim3 gz(B_ / 256, DZ_ / 128);   // 32 x 8 = 256 blocks
  const dim3 gh(B_ / 256, 4);           // head: N=512 -> 32 x 4

  // xs_e = xs@Wx.T + bx  (bf16)
  gemm_bt<0, 0, false><<<gz, blk, 0, stream>>>(xs_b, DX_, Wx_b, DX_, bx, nullptr, nullptr, xse_b, nullptr, DZ_, DX_);
  // ys_e = ys0@Wy.T + by (bf16)
  gemm_bt<0, 0, false><<<gz, blk, 0, stream>>>(ysin_b, DY_, Wy_b, DY_, by, nullptr, nullptr, ys_b, nullptr, DZ_, DY_);
  // cx = xs_e@Wnx.T (bf16)
  gemm_bt<0, 0, false><<<gz, blk, 0, stream>>>(xse_b, DZ_, Wn_b, 3 * DZ_, nullptr, nullptr, nullptr, cx, nullptr, DZ_, DZ_);

  unsigned char* zc8 = z_a8;
  unsigned char* zn8 = z_b8;
  for (int tt = 0; tt < T_; ++tt) {
    // cy = ys_e@Wny.T + bn ; c = cy + cx  (bf16, one GEMM)
    gemm_bt<0, 1, true><<<gz, blk, 0, stream>>>(ys_b, DZ_, Wn_b + DZ_, 3 * DZ_, bn, cx, cy, c, nullptr, DZ_, DZ_);
    if (tt < T_ - 1) {
      // no-grad phase: fp8 z-steps; bf16 shadow only at tt==2's last step (tt=3 input)
      for (int i = 0; i < NN_; ++i) {
        bf16* shadow = (tt == T_ - 2 && i == NN_ - 1) ? z_a : nullptr;
        gemm_f8<<<gz, blk, 0, stream>>>(zc8, Wnz8, c, zn8, shadow);
        unsigned char* t8 = zc8; zc8 = zn8; zn8 = t8;
      }
      // ys_e = tanh(cy + z@Wnz.T)  — fp8 (noise contracts through >=7 later steps)
      gemm_f8<<<gz, blk, 0, stream>>>(zc8, Wnz8, cy, nullptr, ys_b);
    } else {
      // grad-enabled block: bf16 z-steps from the tt=2 shadow
      bf16* zc = z_a;
      bf16* zn = z_b;
      for (int i = 0; i < NN_; ++i) {
        gemm_bt<1, 0, true><<<gz, blk, 0, stream>>>(zc, DZ_, Wn_b + 2 * DZ_, 3 * DZ_, nullptr, c, nullptr, zn, nullptr, DZ_, DZ_);
        bf16* tmp = zc; zc = zn; zn = tmp;
      }
      // ys_e = tanh(cy + z@Wnz.T)  (bf16)
      gemm_bt<1, 0, true><<<gz, blk, 0, stream>>>(zc, DZ_, Wn_b + 2 * DZ_, 3 * DZ_, nullptr, cy, nullptr, ys_b, nullptr, DZ_, DZ_);
    }
  }

  float* outp = (float*)d_out;
  // y_hat | q_hat = sigmoid(ys_e@[Wu;Wq].T + [bu;bq]) — one N=512 GEMM, split store
  gemm_bt<2, 2, false><<<gh, blk, 0, stream>>>(ys_b, DZ_, Wuq_b, DZ_, buq, nullptr, nullptr,
                                               outp, outp + (size_t)B_ * DY_, 2 * DY_, DZ_);
}

// Round 16
// 813.802 us; speedup vs baseline: 3.8884x; 1.0299x over previous
//
#include <hip/hip_runtime.h>
#include <hip/hip_bf16.h>
#include <cstdint>
#include <cstddef>

#define B_   8192
#define DX_  512
#define DZ_  1024
#define DY_  256
#define T_   4
#define NN_  6

typedef float f32x4 __attribute__((ext_vector_type(4)));
typedef short s16x8 __attribute__((ext_vector_type(8)));
typedef long i64x2 __attribute__((ext_vector_type(2)));
typedef __hip_bfloat16 bf16;

__device__ __forceinline__ void gload_lds16(const void* g, void* l) {
  __builtin_amdgcn_global_load_lds(
      (const __attribute__((address_space(1))) void*)g,
      (__attribute__((address_space(3))) void*)l,
      16, 0, 0);
}

__device__ __forceinline__ float bf2f(unsigned short u) {
  union { unsigned int i; float f; } cv; cv.i = ((unsigned int)u) << 16; return cv.f;
}

// fp8 k-permute: within each 64-col group, byte for col n goes to
// perm(n) = g4*16 + slice*8 + j  (g4=(n>>3)&3, slice=(n>>5)&1, j=n&7), so a b128
// LDS read at chunk g4 yields both K=32 slices for mfma_16x16x32_fp8_fp8.
__device__ __forceinline__ int permb(int n) {
  return (n & ~63) | (((n >> 3) & 3) << 4) | (((n >> 5) & 1) << 3) | (n & 7);
}

// ---- one fused conversion kernel: fp32->bf16 copies + bias pack + fp8 images
__device__ __forceinline__ void cv4(const float* __restrict__ s, bf16* __restrict__ d, long i) {
  float4 v = ((const float4*)s)[i];
  ushort4 o;
  bf16 a0 = __float2bfloat16(v.x); o.x = *(unsigned short*)&a0;
  bf16 a1 = __float2bfloat16(v.y); o.y = *(unsigned short*)&a1;
  bf16 a2 = __float2bfloat16(v.z); o.z = *(unsigned short*)&a2;
  bf16 a3 = __float2bfloat16(v.w); o.w = *(unsigned short*)&a3;
  ((ushort4*)d)[i] = o;
}
__device__ __forceinline__ void cv4f8(const float* __restrict__ src, unsigned char* __restrict__ dst,
                                      long row, int k0, int srcld, int srcoff) {
  float4 v = *(const float4*)(src + row * srcld + srcoff + k0);
  int p = __builtin_amdgcn_cvt_pk_fp8_f32(v.x, v.y, 0, 0);
  p = __builtin_amdgcn_cvt_pk_fp8_f32(v.z, v.w, p, 1);
  *(int*)(dst + row * DZ_ + permb(k0)) = p;   // k0 % 4 == 0 -> 4 contiguous bytes
}

__global__ void cvt_all_kernel(const float* __restrict__ Wn, const float* __restrict__ Wx,
                               const float* __restrict__ Wy, const float* __restrict__ Wu,
                               const float* __restrict__ Wq, const float* __restrict__ xs,
                               const float* __restrict__ ys0, const float* __restrict__ zs0,
                               const float* __restrict__ bu, const float* __restrict__ bq,
                               bf16* __restrict__ Wn_b, bf16* __restrict__ Wx_b,
                               bf16* __restrict__ Wy_b, bf16* __restrict__ Wuq_b,
                               bf16* __restrict__ xs_b, bf16* __restrict__ ysin_b,
                               float* __restrict__ buq,
                               unsigned char* __restrict__ Wnz8, unsigned char* __restrict__ z_a8) {
  const long NWN = (long)DZ_ * 3 * DZ_ / 4, NWX = (long)DZ_ * DX_ / 4,
             NWY = (long)DZ_ * DY_ / 4,     NWU = (long)DY_ * DZ_ / 4,
             NXS = (long)B_ * DX_ / 4,      NYS = (long)B_ * DY_ / 4,
             NBQ = 2 * DY_ / 4,
             NW8 = (long)DZ_ * DZ_ / 4,     NZ8 = (long)B_ * DZ_ / 4;
  const long total = NWN + NWX + NWY + 2 * NWU + NXS + NYS + NBQ + NW8 + NZ8;
  for (long i = (long)blockIdx.x * blockDim.x + threadIdx.x; i < total;
       i += (long)gridDim.x * blockDim.x) {
    long j = i;
    if (j < NWN) { cv4(Wn, Wn_b, j); continue; } j -= NWN;
    if (j < NWX) { cv4(Wx, Wx_b, j); continue; } j -= NWX;
    if (j < NWY) { cv4(Wy, Wy_b, j); continue; } j -= NWY;
    if (j < NWU) { cv4(Wu, Wuq_b, j); continue; } j -= NWU;
    if (j < NWU) { cv4(Wq, Wuq_b + (size_t)DY_ * DZ_, j); continue; } j -= NWU;
    if (j < NXS) { cv4(xs, xs_b, j); continue; } j -= NXS;
    if (j < NYS) { cv4(ys0, ysin_b, j); continue; } j -= NYS;
    if (j < NBQ) {
      float4 v = (j < DY_ / 4) ? ((const float4*)bu)[j] : ((const float4*)bq)[j - DY_ / 4];
      ((float4*)buq)[j] = v; continue;
    } j -= NBQ;
    if (j < NW8) {  // Wnz (cols 2048..3071 of Wn) -> fp8 k-permuted
      long e = j * 4; long row = e >> 10; int k0 = (int)(e & 1023);
      cv4f8(Wn, Wnz8, row, k0, 3 * DZ_, 2 * DZ_); continue;
    } j -= NW8;
    {   // zs0 -> fp8 k-permuted
      long e = j * 4; long row = e >> 10; int k0 = (int)(e & 1023);
      cv4f8(zs0, z_a8, row, k0, DZ_, 0);
    }
  }
}

// ================= bf16 GEMM (r10/r13-proven: BK=64, two-half lgkm schedule) =========
template<int ACT, int MODE, bool HASADD>   // ACT: 0 none, 1 tanh, 2 sigmoid
__global__ __launch_bounds__(512, 2)
void gemm_bt(const bf16* __restrict__ A, int lda,
             const bf16* __restrict__ W, int ldw,
             const float* __restrict__ bias,
             const bf16* __restrict__ add1,
             bf16* __restrict__ out_pre,
             void* __restrict__ out, void* __restrict__ out2,
             int N, int K)
{
  __shared__ __align__(16) char ldsc[3 * 49152];   // [buf][A 32KB | B 16KB]
  const int t    = threadIdx.x;
  const int lane = t & 63;
  const int wave = t >> 6;
  const int m0 = blockIdx.x * 256;
  const int n0 = blockIdx.y * 128;

  const int srow = t >> 3;
  const int q    = (t & 7) ^ ((t >> 3) & 7);
  const bf16* gA = A + (size_t)(m0 + srow) * lda + q * 8;
  const bf16* gB = W + (size_t)(n0 + srow) * ldw + q * 8;
  const int wb = wave * 1024;

  auto stage = [&](int kt) {
    char* base = ldsc + (kt % 3) * 49152;
    const int ko = kt << 6;
#pragma unroll
    for (int i = 0; i < 4; ++i)
      gload_lds16(gA + (size_t)(i * 64) * lda + ko, base + i * 8192 + wb);
#pragma unroll
    for (int i = 0; i < 2; ++i)
      gload_lds16(gB + (size_t)(i * 64) * ldw + ko, base + 32768 + i * 8192 + wb);
  };

  const int mo = (wave >> 1) * 64;
  const int no = (wave & 1) * 64;
  const int fr = lane & 15;
  const int g4 = lane >> 4;
  const int rb = g4 * 4;

  const int NT = K >> 6;

  float bv[4] = {0.f, 0.f, 0.f, 0.f};
  if (bias) {
#pragma unroll
    for (int j = 0; j < 4; ++j) bv[j] = bias[n0 + no + j * 16 + fr];
  }
  unsigned short adr[4][4][4];
  if (HASADD && MODE != 1) {
#pragma unroll
    for (int f = 0; f < 4; ++f)
#pragma unroll
      for (int j = 0; j < 4; ++j) {
        const unsigned short* p = (const unsigned short*)add1
            + (size_t)(m0 + mo + f * 16 + rb) * N + (n0 + no + j * 16 + fr);
#pragma unroll
        for (int r = 0; r < 4; ++r) adr[f][j][r] = p[(size_t)r * N];
      }
  }
  __builtin_amdgcn_sched_barrier(0);
  stage(0);
  stage(1);
  __builtin_amdgcn_sched_barrier(0);

  f32x4 acc[4][4];
#pragma unroll
  for (int f = 0; f < 4; ++f)
#pragma unroll
    for (int j = 0; j < 4; ++j)
#pragma unroll
      for (int r = 0; r < 4; ++r) {
        float v = bv[j];
        if (HASADD && MODE != 1) v += bf2f(adr[f][j][r]);
        acc[f][j][r] = v;
      }

  s16x8 a0[4], b0[4], a1[4], b1[4];
  auto ldfrags = [&](int kt, int s, s16x8* fa, s16x8* fb) {
    const char* pA = ldsc + (kt % 3) * 49152;
    const char* pB = pA + 32768;
    const int cb = ((s * 4 + g4) ^ (fr & 7)) * 16;
#pragma unroll
    for (int f = 0; f < 4; ++f) fa[f] = *(const s16x8*)(pA + (mo + f * 16 + fr) * 128 + cb);
#pragma unroll
    for (int j = 0; j < 4; ++j) fb[j] = *(const s16x8*)(pB + (no + j * 16 + fr) * 128 + cb);
  };
  auto domfma = [&](const s16x8* fa, const s16x8* fb) {
    __builtin_amdgcn_s_setprio(1);
#pragma unroll
    for (int f = 0; f < 4; ++f)
#pragma unroll
      for (int j = 0; j < 4; ++j)
        acc[f][j] = __builtin_amdgcn_mfma_f32_16x16x32_bf16(fa[f], fb[j], acc[f][j], 0, 0, 0);
    __builtin_amdgcn_s_setprio(0);
  };

  asm volatile("s_waitcnt vmcnt(6)" ::: "memory");
  __builtin_amdgcn_s_barrier();
  __builtin_amdgcn_sched_barrier(0);

  for (int kt = 0; kt < NT; ++kt) {
    ldfrags(kt, 0, a0, b0);
    ldfrags(kt, 1, a1, b1);
    if (kt + 2 < NT) stage(kt + 2);
    __builtin_amdgcn_sched_barrier(0);
    asm volatile("s_waitcnt lgkmcnt(8)" ::: "memory");
    __builtin_amdgcn_sched_barrier(0);
    domfma(a0, b0);
    asm volatile("s_waitcnt lgkmcnt(0)" ::: "memory");
    __builtin_amdgcn_sched_barrier(0);
    domfma(a1, b1);
    if (kt + 2 < NT)      asm volatile("s_waitcnt vmcnt(6)" ::: "memory");
    else if (kt + 1 < NT) asm volatile("s_waitcnt vmcnt(0)" ::: "memory");
    if (kt + 1 < NT) {
      __builtin_amdgcn_s_barrier();
      __builtin_amdgcn_sched_barrier(0);
    }
  }

#pragma unroll
  for (int f = 0; f < 4; ++f) {
#pragma unroll
    for (int j = 0; j < 4; ++j) {
      const int n = n0 + no + j * 16 + fr;
#pragma unroll
      for (int r = 0; r < 4; ++r) {
        const int m = m0 + mo + f * 16 + rb + r;
        float v = acc[f][j][r];
        if (MODE == 1) {
          out_pre[(size_t)m * N + n] = __float2bfloat16(v);
          v += bf2f(((const unsigned short*)add1)[(size_t)m * N + n]);
        }
        if (ACT == 1)      { float e = __expf(2.f * v); v = 1.f - 2.f / (e + 1.f); }
        else if (ACT == 2) v = 1.f / (1.f + __expf(-v));
        if (MODE == 2) {
          if (n < DY_) ((float*)out)[(size_t)m * DY_ + n] = v;
          else         ((float*)out2)[(size_t)m * DY_ + (n - DY_)] = v;
        } else {
          ((bf16*)out)[(size_t)m * N + n] = __float2bfloat16(v);
        }
      }
    }
  }
}

// ================= fp8 GEMM (r10-proven: 4x24KB buffers, depth-3 prefetch) =========
// out = tanh(add1 + A8 @ W8.T); A8/W8 fp8 e4m3, k-permuted global layout.
// out8 (fp8, permuted) optional; out16 (bf16) optional.
__global__ __launch_bounds__(512, 2)
void gemm_f8(const unsigned char* __restrict__ A8,
             const unsigned char* __restrict__ W8,
             const bf16* __restrict__ add1,
             unsigned char* __restrict__ out8,
             bf16* __restrict__ out16)
{
  __shared__ __align__(16) char ldsc[4 * 24576];   // [buf][A 16KB | B 8KB]
  const int t    = threadIdx.x;
  const int lane = t & 63;
  const int wave = t >> 6;
  const int m0 = blockIdx.x * 256;
  const int n0 = blockIdx.y * 128;

  const int srow = t >> 2;
  const int q    = (t & 3) ^ ((t >> 3) & 3);
  const unsigned char* gA = A8 + (size_t)(m0 + srow) * DZ_ + q * 16;
  const unsigned char* gB = W8 + (size_t)(n0 + srow) * DZ_ + q * 16;
  const int wb = wave * 1024;

  auto stage = [&](int kt) {                 // 3 gloads: A 2x8KB, B 1x8KB
    char* base = ldsc + (kt & 3) * 24576;
    const int ko = kt << 6;
    gload_lds16(gA + ko, base + wb);
    gload_lds16(gA + (size_t)128 * DZ_ + ko, base + 8192 + wb);
    gload_lds16(gB + ko, base + 16384 + wb);
  };

  const int mo = (wave >> 1) * 64;
  const int no = (wave & 1) * 64;
  const int fr = lane & 15;
  const int g4 = lane >> 4;
  const int rb = g4 * 4;
  const int cb = (g4 ^ ((fr >> 1) & 3)) * 16;   // swizzled 16B chunk

  const int NT = DZ_ >> 6;                      // 16

  unsigned short adr[4][4][4];
#pragma unroll
  for (int f = 0; f < 4; ++f)
#pragma unroll
    for (int j = 0; j < 4; ++j) {
      const unsigned short* p = (const unsigned short*)add1
          + (size_t)(m0 + mo + f * 16 + rb) * DZ_ + (n0 + no + j * 16 + fr);
#pragma unroll
      for (int r = 0; r < 4; ++r) adr[f][j][r] = p[(size_t)r * DZ_];
    }
  __builtin_amdgcn_sched_barrier(0);
  stage(0); stage(1); stage(2);
  __builtin_amdgcn_sched_barrier(0);

  f32x4 acc[4][4];
#pragma unroll
  for (int f = 0; f < 4; ++f)
#pragma unroll
    for (int j = 0; j < 4; ++j)
#pragma unroll
      for (int r = 0; r < 4; ++r) acc[f][j][r] = bf2f(adr[f][j][r]);

  asm volatile("s_waitcnt vmcnt(6)" ::: "memory");   // tile 0 resident
  __builtin_amdgcn_s_barrier();
  __builtin_amdgcn_sched_barrier(0);

  for (int kt = 0; kt < NT; ++kt) {
    const char* pA = ldsc + (kt & 3) * 24576;
    const char* pB = pA + 16384;
    i64x2 av[4], bv[4];
#pragma unroll
    for (int f = 0; f < 4; ++f) av[f] = *(const i64x2*)(pA + (mo + f * 16 + fr) * 64 + cb);
#pragma unroll
    for (int j = 0; j < 4; ++j) bv[j] = *(const i64x2*)(pB + (no + j * 16 + fr) * 64 + cb);
    if (kt + 3 < NT) stage(kt + 3);
    __builtin_amdgcn_sched_barrier(0);
    asm volatile("s_waitcnt lgkmcnt(0)" ::: "memory");
    __builtin_amdgcn_sched_barrier(0);
    __builtin_amdgcn_s_setprio(1);
#pragma unroll
    for (int f = 0; f < 4; ++f)
#pragma unroll
      for (int j = 0; j < 4; ++j) {
        acc[f][j] = __builtin_amdgcn_mfma_f32_16x16x32_fp8_fp8(av[f][0], bv[j][0], acc[f][j], 0, 0, 0);
        acc[f][j] = __builtin_amdgcn_mfma_f32_16x16x32_fp8_fp8(av[f][1], bv[j][1], acc[f][j], 0, 0, 0);
      }
    __builtin_amdgcn_s_setprio(0);
    const int rem = NT - 1 - kt;
    if (rem >= 3)      asm volatile("s_waitcnt vmcnt(6)" ::: "memory");
    else if (rem == 2) asm volatile("s_waitcnt vmcnt(3)" ::: "memory");
    else if (rem == 1) asm volatile("s_waitcnt vmcnt(0)" ::: "memory");
    if (rem >= 1) {
      __builtin_amdgcn_s_barrier();
      __builtin_amdgcn_sched_barrier(0);
    }
  }

  // epilogue: tanh; fp8 (permuted) and/or bf16 outputs
#pragma unroll
  for (int f = 0; f < 4; ++f) {
#pragma unroll
    for (int j = 0; j < 4; ++j) {
      const int n = n0 + no + j * 16 + fr;
      const int np = permb(n);
#pragma unroll
      for (int r = 0; r < 4; ++r) {
        const int m = m0 + mo + f * 16 + rb + r;
        float v = acc[f][j][r];
        float e = __expf(2.f * v); v = 1.f - 2.f / (e + 1.f);
        if (out8)  out8[(size_t)m * DZ_ + np] =
            (unsigned char)__builtin_amdgcn_cvt_pk_fp8_f32(v, v, 0, 0);
        if (out16) out16[(size_t)m * DZ_ + n] = __float2bfloat16(v);
      }
    }
  }
}

extern "C" void kernel_launch(void* const* d_in, const int* in_sizes, int n_in,
                              void* d_out, int out_size, void* d_ws, size_t ws_size,
                              hipStream_t stream) {
  const float* xs  = (const float*)d_in[0];
  const float* Wx  = (const float*)d_in[1];
  const float* bx  = (const float*)d_in[2];
  const float* Wy  = (const float*)d_in[3];
  const float* by  = (const float*)d_in[4];
  const float* Wn  = (const float*)d_in[5];
  const float* bn  = (const float*)d_in[6];
  const float* Wu  = (const float*)d_in[7];
  const float* bu  = (const float*)d_in[8];
  const float* Wq  = (const float*)d_in[9];
  const float* bq  = (const float*)d_in[10];
  const float* ys0 = (const float*)d_in[11];
  const float* zs0 = (const float*)d_in[12];

  char* ws = (char*)d_ws;
  size_t off = 0;
  auto take = [&](size_t bytes) -> char* {
    char* p = ws + off;
    off += (bytes + 255) & ~(size_t)255;
    return p;
  };

  bf16*  Wn_b   = (bf16*)take((size_t)DZ_ * 3 * DZ_ * 2);
  bf16*  Wx_b   = (bf16*)take((size_t)DZ_ * DX_ * 2);
  bf16*  Wy_b   = (bf16*)take((size_t)DZ_ * DY_ * 2);
  bf16*  Wuq_b  = (bf16*)take((size_t)2 * DY_ * DZ_ * 2);
  float* buq    = (float*)take((size_t)2 * DY_ * 4);
  bf16*  ys_b   = (bf16*)take((size_t)B_ * DZ_ * 2);
  bf16*  z_a    = (bf16*)take((size_t)B_ * DZ_ * 2);
  bf16*  z_b    = (bf16*)take((size_t)B_ * DZ_ * 2);
  bf16*  cx     = (bf16*)take((size_t)B_ * DZ_ * 2);
  bf16*  cy     = (bf16*)take((size_t)B_ * DZ_ * 2);
  bf16*  c      = (bf16*)take((size_t)B_ * DZ_ * 2);
  unsigned char* Wnz8 = (unsigned char*)take((size_t)DZ_ * DZ_);
  unsigned char* z_a8 = (unsigned char*)take((size_t)B_ * DZ_);
  unsigned char* z_b8 = (unsigned char*)take((size_t)B_ * DZ_);
  // aliases into regions not yet live at time of use:
  bf16* xs_b   = c;                                         // dead before c first written
  bf16* ysin_b = (bf16*)((char*)c + (size_t)B_ * DX_ * 2);  // 8.4+4.2 MB <= 16.7 MB
  bf16* xse_b  = cy;                                        // dead before cy first written

  cvt_all_kernel<<<2048, 256, 0, stream>>>(Wn, Wx, Wy, Wu, Wq, xs, ys0, zs0, bu, bq,
                                           Wn_b, Wx_b, Wy_b, Wuq_b,
                                           xs_b, ysin_b, buq, Wnz8, z_a8);

  const dim3 blk(512);
  const dim3 gz(B_ / 256, DZ_ / 128);   // 32 x 8 = 256 blocks = 1/CU
  const dim3 gh(B_ / 256, 4);           // head: N=512 -> 32 x 4

  // xs_e = xs@Wx.T + bx  (bf16)
  gemm_bt<0, 0, false><<<gz, blk, 0, stream>>>(xs_b, DX_, Wx_b, DX_, bx, nullptr, nullptr, xse_b, nullptr, DZ_, DX_);
  // ys_e = ys0@Wy.T + by (bf16)
  gemm_bt<0, 0, false><<<gz, blk, 0, stream>>>(ysin_b, DY_, Wy_b, DY_, by, nullptr, nullptr, ys_b, nullptr, DZ_, DY_);
  // cx = xs_e@Wnx.T (bf16)
  gemm_bt<0, 0, false><<<gz, blk, 0, stream>>>(xse_b, DZ_, Wn_b, 3 * DZ_, nullptr, nullptr, nullptr, cx, nullptr, DZ_, DZ_);

  unsigned char* zc8 = z_a8;
  unsigned char* zn8 = z_b8;
  for (int tt = 0; tt < T_; ++tt) {
    // cy = ys_e@Wny.T + bn ; c = cy + cx  (bf16, one GEMM)
    gemm_bt<0, 1, true><<<gz, blk, 0, stream>>>(ys_b, DZ_, Wn_b + DZ_, 3 * DZ_, bn, cx, cy, c, nullptr, DZ_, DZ_);
    if (tt < T_ - 1) {
      // no-grad phase: fp8 z-steps; bf16 shadow only at tt==2's last step (tt=3 input)
      for (int i = 0; i < NN_; ++i) {
        bf16* shadow = (tt == T_ - 2 && i == NN_ - 1) ? z_a : nullptr;
        gemm_f8<<<gz, blk, 0, stream>>>(zc8, Wnz8, c, zn8, shadow);
        unsigned char* t8 = zc8; zc8 = zn8; zn8 = t8;
      }
      // ys_e = tanh(cy + z@Wnz.T)  — fp8 (noise contracts through >=7 later steps)
      gemm_f8<<<gz, blk, 0, stream>>>(zc8, Wnz8, cy, nullptr, ys_b);
    } else {
      // grad-enabled block: bf16 z-steps from the tt=2 shadow
      bf16* zc = z_a;
      bf16* zn = z_b;
      for (int i = 0; i < NN_; ++i) {
        gemm_bt<1, 0, true><<<gz, blk, 0, stream>>>(zc, DZ_, Wn_b + 2 * DZ_, 3 * DZ_, nullptr, c, nullptr, zn, nullptr, DZ_, DZ_);
        bf16* tmp = zc; zc = zn; zn = tmp;
      }
      // ys_e = tanh(cy + z@Wnz.T)  (bf16)
      gemm_bt<1, 0, true><<<gz, blk, 0, stream>>>(zc, DZ_, Wn_b + 2 * DZ_, 3 * DZ_, nullptr, cy, nullptr, ys_b, nullptr, DZ_, DZ_);
    }
  }

  float* outp = (float*)d_out;
  // y_hat | q_hat = sigmoid(ys_e@[Wu;Wq].T + [bu;bq]) — one N=512 GEMM, split store
  gemm_bt<2, 2, false><<<gh, blk, 0, stream>>>(ys_b, DZ_, Wuq_b, DZ_, buq, nullptr, nullptr,
                                               outp, outp + (size_t)B_ * DY_, 2 * DY_, DZ_);
}